// Round 1
// baseline (59.839 us; speedup 1.0000x reference)
//
#include <hip/hip_runtime.h>
#include <math.h>

#define BATCH 128
#define NPRE  1024
#define NPOST 256
#define CH    32

__device__ __forceinline__ float lambertw0_f(float z) {
    // Principal branch for z in [-1/e, 0); mirrors reference (clip + init + 12 Halley)
    const float INV_E = 0.36787944117144233f;
    float zc = fminf(fmaxf(z, -INV_E + 1e-8f), -1e-30f);
    float w;
    if (zc < -0.2f) {
        w = -1.0f + sqrtf(2.0f * (1.0f + 2.718281828459045f * zc));
    } else {
        w = zc * (1.0f - zc);
    }
#pragma unroll
    for (int it = 0; it < 12; ++it) {
        float ew  = expf(w);
        float f   = w * ew - zc;
        float wp1 = w + 1.0f;
        w = w - f / (ew * wp1 - (w + 2.0f) * f / (2.0f * wp1));
    }
    return w;
}

__global__ __launch_bounds__(256)
void ttfs_kernel(const float* __restrict__ spikes,   // (BATCH, NPRE)
                 const float* __restrict__ Wt,       // (NPRE, NPOST)
                 float* __restrict__ out)            // (BATCH, NPOST)
{
    __shared__ float skey[NPRE + 1];   // sorted spike times, +inf pad
    __shared__ float earr[NPRE + 1];   // exp(s), +inf pad
    __shared__ float searr[NPRE];      // s*exp(s)
    __shared__ int   sidx[NPRE];       // argsort indices

    const int b   = blockIdx.x;
    const int tid = threadIdx.x;

    // ---- load row ----
#pragma unroll
    for (int i = 0; i < NPRE / 256; ++i) {
        int k = tid + i * 256;
        skey[k] = spikes[b * NPRE + k];
        sidx[k] = k;
    }
    __syncthreads();

    // ---- bitonic sort by (key asc, idx asc) == stable argsort ----
    for (int size = 2; size <= NPRE; size <<= 1) {
        for (int stride = size >> 1; stride > 0; stride >>= 1) {
#pragma unroll
            for (int u = 0; u < NPRE / 512; ++u) {
                int t = tid + u * 256;
                int i = ((t & ~(stride - 1)) << 1) | (t & (stride - 1));
                int j = i | stride;
                float ki = skey[i], kj = skey[j];
                int   ii = sidx[i], ij = sidx[j];
                bool up = ((i & size) == 0);
                bool sw = up ? ((ki > kj) || (ki == kj && ii > ij))
                             : ((ki < kj) || (ki == kj && ii < ij));
                if (sw) {
                    skey[i] = kj; skey[j] = ki;
                    sidx[i] = ij; sidx[j] = ii;
                }
            }
            __syncthreads();
        }
    }

    // ---- precompute exp tables ----
#pragma unroll
    for (int i = 0; i < NPRE / 256; ++i) {
        int k = tid + i * 256;
        float s = skey[k];
        float e = expf(s);
        earr[k]  = e;
        searr[k] = s * e;
    }
    if (tid == 0) { skey[NPRE] = INFINITY; earr[NPRE] = INFINITY; }
    __syncthreads();

    // ---- per-neuron scan with membrane-crossing gate ----
    const int j = tid;                      // one post neuron per thread
    const float* __restrict__ Wcol = Wt + j;

    float A = 0.0f, Bq = 0.0f;
    float fA = 0.0f, fB = 0.0f;
    int   fk = -1;
    bool  done = false;

    float wv[CH];
#pragma unroll
    for (int i = 0; i < CH; ++i) wv[i] = Wcol[sidx[i] * NPOST];

    for (int kb = 0; kb < NPRE; kb += CH) {
        float wn[CH];
        const int nb = kb + CH;
        if (nb < NPRE) {
#pragma unroll
            for (int i = 0; i < CH; ++i) wn[i] = Wcol[sidx[nb + i] * NPOST];
        }
#pragma unroll
        for (int i = 0; i < CH; ++i) {
            const int k = kb + i;
            const float w = wv[i];
            A  = fmaf(w, earr[k],  A);
            Bq = fmaf(w, searr[k], Bq);
            if (!done) {
                // fire in window [s_k, s_{k+1}]  <=>  V(s_{k+1}) >= 1
                float gate = fmaf(A, skey[k + 1], -Bq);
                if (gate >= earr[k + 1]) { fA = A; fB = Bq; fk = k; done = true; }
            }
        }
        if (__all(done)) break;
        if (nb < NPRE) {
#pragma unroll
            for (int i = 0; i < CH; ++i) wv[i] = wn[i];
        }
    }

    // ---- resolve candidate (Lambert W once per thread) ----
    const float INV_E = 0.36787944117144233f;
    float result = INFINITY;
    if (fk >= 0) {
        float r  = fB / fA;
        float ez = expf(fminf(fmaxf(r, -30.0f), 30.0f));
        float z  = -ez / fA;
        bool valid = (fA > 0.0f) && (z >= -INV_E);
        float t = r - lambertw0_f(z);
        bool ok = valid && (t >= skey[fk]) && (fk == NPRE - 1 || t <= skey[fk + 1]);
        if (ok) {
            result = t;
        } else {
            // rare fp-edge fallback: faithful scalar scan from fk+1
            float A2 = fA, B2 = fB;
            for (int k = fk + 1; k < NPRE; ++k) {
                float w = Wcol[sidx[k] * NPOST];
                A2 = fmaf(w, earr[k],  A2);
                B2 = fmaf(w, searr[k], B2);
                if (A2 <= 0.0f) continue;
                float r2  = B2 / A2;
                float ez2 = expf(fminf(fmaxf(r2, -30.0f), 30.0f));
                float z2  = -ez2 / A2;
                if (z2 < -INV_E) continue;
                float t2 = r2 - lambertw0_f(z2);
                if (t2 < skey[k]) continue;
                if (k < NPRE - 1 && t2 > skey[k + 1]) continue;
                result = t2;
                break;
            }
        }
    }
    out[b * NPOST + j] = result;
}

extern "C" void kernel_launch(void* const* d_in, const int* in_sizes, int n_in,
                              void* d_out, int out_size, void* d_ws, size_t ws_size,
                              hipStream_t stream) {
    const float* spikes = (const float*)d_in[0];   // (128, 1024) f32
    const float* weights = (const float*)d_in[1];  // (1024, 256) f32
    float* out = (float*)d_out;                    // (128, 256) f32
    ttfs_kernel<<<dim3(BATCH), dim3(NPOST), 0, stream>>>(spikes, weights, out);
}

// Round 2
// 50.434 us; speedup vs baseline: 1.1865x; 1.1865x over previous
//
#include <hip/hip_runtime.h>
#include <math.h>

#define BATCH 128
#define NPRE  1024
#define NPOST 256
#define NCH   4      // k-chunks per neuron
#define CLEN  256    // NPRE / NCH
#define NJ    128    // neurons per block (NPOST/2)
#define CH    32     // weight prefetch batch

__device__ __forceinline__ float lambertw0_f(float z) {
    // Principal branch for z in [-1/e, 0); mirrors reference (clip + init + 12 Halley)
    const float INV_E = 0.36787944117144233f;
    float zc = fminf(fmaxf(z, -INV_E + 1e-8f), -1e-30f);
    float w;
    if (zc < -0.2f) {
        w = -1.0f + sqrtf(2.0f * (1.0f + 2.718281828459045f * zc));
    } else {
        w = zc * (1.0f - zc);
    }
#pragma unroll
    for (int it = 0; it < 12; ++it) {
        float ew  = expf(w);
        float f   = w * ew - zc;
        float wp1 = w + 1.0f;
        w = w - f / (ew * wp1 - (w + 2.0f) * f / (2.0f * wp1));
    }
    return w;
}

__global__ __launch_bounds__(512)
void ttfs_kernel(const float* __restrict__ spikes,   // (BATCH, NPRE)
                 const float* __restrict__ Wt,       // (NPRE, NPOST)
                 float* __restrict__ out)            // (BATCH, NPOST)
{
    __shared__ unsigned long long pairs[NPRE];   // (keybits<<32)|idx, sorted
    __shared__ float skey[NPRE + 1];
    __shared__ float earr[NPRE + 1];
    __shared__ float searr[NPRE];
    __shared__ float cA[NCH][NJ], cB[NCH][NJ];   // chunk sums
    __shared__ int   ffk[NCH][NJ];               // chunk-found k (-1 none)
    __shared__ float ffA[NCH][NJ], ffB[NCH][NJ];

    const int tid = threadIdx.x;
    const int b   = (int)blockIdx.x >> 1;
    const int h   = (int)blockIdx.x & 1;

    // ---- load + pack (key asc, idx asc) == u64 asc for positive floats ----
#pragma unroll
    for (int i = 0; i < NPRE / 512; ++i) {
        int k = tid + i * 512;
        float s = spikes[b * NPRE + k];
        pairs[k] = (((unsigned long long)__float_as_uint(s)) << 32) | (unsigned)k;
    }
    __syncthreads();

    // ---- bitonic sort on packed u64, 1 compare-exchange per thread/phase ----
    for (int size = 2; size <= NPRE; size <<= 1) {
        for (int stride = size >> 1; stride > 0; stride >>= 1) {
            int t = tid;
            int i = ((t & ~(stride - 1)) << 1) | (t & (stride - 1));
            int j = i | stride;
            unsigned long long pi = pairs[i], pj = pairs[j];
            bool up = ((i & size) == 0);
            if (up ? (pi > pj) : (pi < pj)) { pairs[i] = pj; pairs[j] = pi; }
            __syncthreads();
        }
    }

    // ---- exp tables ----
#pragma unroll
    for (int i = 0; i < NPRE / 512; ++i) {
        int k = tid + i * 512;
        float s = __uint_as_float((unsigned)(pairs[k] >> 32));
        float e = expf(s);
        skey[k]  = s;
        earr[k]  = e;
        searr[k] = s * e;
    }
    if (tid == 0) { skey[NPRE] = INFINITY; earr[NPRE] = INFINITY; }
    __syncthreads();

    // ---- chunked scan: 4 chunk-threads per neuron ----
    const int c  = tid >> 7;         // 0..3
    const int jj = tid & (NJ - 1);   // 0..127
    const int j  = h * NJ + jj;
    const float* __restrict__ Wcol = Wt + j;
    const int k0 = c * CLEN;

    // pass 1: chunk-local sums (chunk 3's sums are never used as offsets)
    float A = 0.0f, Bq = 0.0f;
    if (c < NCH - 1) {
        for (int kb = 0; kb < CLEN; kb += CH) {
            float wv[CH];
#pragma unroll
            for (int i = 0; i < CH; ++i) {
                int idx = (int)(unsigned)(pairs[k0 + kb + i] & 0xffffffffULL);
                wv[i] = Wcol[idx * NPOST];
            }
#pragma unroll
            for (int i = 0; i < CH; ++i) {
                A  = fmaf(wv[i], earr[k0 + kb + i],  A);
                Bq = fmaf(wv[i], searr[k0 + kb + i], Bq);
            }
        }
    }
    cA[c][jj] = A; cB[c][jj] = Bq;
    __syncthreads();

    // pass 2: exclusive prefix over chunks
    float offA = 0.0f, offB = 0.0f;
    for (int cc = 0; cc < c; ++cc) { offA += cA[cc][jj]; offB += cB[cc][jj]; }

    // pass 3: scan chunk for first membrane crossing: V(s_{k+1}) >= 1
    A = offA; Bq = offB;
    int   fk = -1; float fA = 0.0f, fB = 0.0f;
    bool  done = false;

    float wv[CH];
#pragma unroll
    for (int i = 0; i < CH; ++i) {
        int idx = (int)(unsigned)(pairs[k0 + i] & 0xffffffffULL);
        wv[i] = Wcol[idx * NPOST];
    }
    for (int kb = 0; kb < CLEN; kb += CH) {
        float wn[CH];
        const int nb = kb + CH;
        if (nb < CLEN) {
#pragma unroll
            for (int i = 0; i < CH; ++i) {
                int idx = (int)(unsigned)(pairs[k0 + nb + i] & 0xffffffffULL);
                wn[i] = Wcol[idx * NPOST];
            }
        }
#pragma unroll
        for (int i = 0; i < CH; ++i) {
            const int k = k0 + kb + i;
            A  = fmaf(wv[i], earr[k],  A);
            Bq = fmaf(wv[i], searr[k], Bq);
            if (!done) {
                float gate = fmaf(A, skey[k + 1], -Bq);
                if (gate >= earr[k + 1]) { fA = A; fB = Bq; fk = k; done = true; }
            }
        }
        if (__all(done)) break;
        if (nb < CLEN) {
#pragma unroll
            for (int i = 0; i < CH; ++i) wv[i] = wn[i];
        }
    }
    ffk[c][jj] = fk; ffA[c][jj] = fA; ffB[c][jj] = fB;
    __syncthreads();

    // ---- resolve: one thread per neuron picks earliest chunk, Lambert W once ----
    if (tid < NJ) {
        const int jr = tid;
        int fk2 = -1; float fA2 = 0.0f, fB2 = 0.0f;
#pragma unroll
        for (int cc = 0; cc < NCH; ++cc) {
            int k = ffk[cc][jr];
            if (fk2 < 0 && k >= 0) { fk2 = k; fA2 = ffA[cc][jr]; fB2 = ffB[cc][jr]; }
        }
        float result = INFINITY;
        const float INV_E = 0.36787944117144233f;
        const float* __restrict__ Wc2 = Wt + h * NJ + jr;
        if (fk2 >= 0) {
            float r  = fB2 / fA2;
            float ez = expf(fminf(fmaxf(r, -30.0f), 30.0f));
            float z  = -ez / fA2;
            bool valid = (fA2 > 0.0f) && (z >= -INV_E);
            float t = r - lambertw0_f(z);
            bool ok = valid && (t >= skey[fk2]) && (fk2 == NPRE - 1 || t <= skey[fk2 + 1]);
            if (ok) {
                result = t;
            } else {
                // rare fp-edge fallback: faithful sequential scan from fk2+1
                float A2 = fA2, B2 = fB2;
                for (int k = fk2 + 1; k < NPRE; ++k) {
                    int idx = (int)(unsigned)(pairs[k] & 0xffffffffULL);
                    float w = Wc2[idx * NPOST];
                    A2 = fmaf(w, earr[k],  A2);
                    B2 = fmaf(w, searr[k], B2);
                    if (A2 <= 0.0f) continue;
                    float r2  = B2 / A2;
                    float ez2 = expf(fminf(fmaxf(r2, -30.0f), 30.0f));
                    float z2  = -ez2 / A2;
                    if (z2 < -INV_E) continue;
                    float t2 = r2 - lambertw0_f(z2);
                    if (t2 < skey[k]) continue;
                    if (k < NPRE - 1 && t2 > skey[k + 1]) continue;
                    result = t2;
                    break;
                }
            }
        }
        out[b * NPOST + h * NJ + jr] = result;
    }
}

extern "C" void kernel_launch(void* const* d_in, const int* in_sizes, int n_in,
                              void* d_out, int out_size, void* d_ws, size_t ws_size,
                              hipStream_t stream) {
    const float* spikes  = (const float*)d_in[0];   // (128, 1024) f32
    const float* weights = (const float*)d_in[1];   // (1024, 256) f32
    float* outp = (float*)d_out;                    // (128, 256) f32
    ttfs_kernel<<<dim3(BATCH * 2), dim3(512), 0, stream>>>(spikes, weights, outp);
}

// Round 3
// 31.100 us; speedup vs baseline: 1.9241x; 1.6217x over previous
//
#include <hip/hip_runtime.h>
#include <math.h>

#define BATCH 128
#define NPRE  1024
#define NPOST 256
#define NCH   8      // k-chunks per neuron
#define CLEN  128    // NPRE / NCH
#define NJ    128    // neurons per block (NPOST/2)
#define CH    16     // weight prefetch batch

__device__ __forceinline__ float lambertw0_f(float z) {
    // Principal branch for z in [-1/e, 0); mirrors reference (clip + init + 12 Halley)
    const float INV_E = 0.36787944117144233f;
    float zc = fminf(fmaxf(z, -INV_E + 1e-8f), -1e-30f);
    float w;
    if (zc < -0.2f) {
        w = -1.0f + sqrtf(2.0f * (1.0f + 2.718281828459045f * zc));
    } else {
        w = zc * (1.0f - zc);
    }
#pragma unroll
    for (int it = 0; it < 12; ++it) {
        float ew  = expf(w);
        float f   = w * ew - zc;
        float wp1 = w + 1.0f;
        w = w - f / (ew * wp1 - (w + 2.0f) * f / (2.0f * wp1));
    }
    return w;
}

__device__ __forceinline__ unsigned long long shflxor64(unsigned long long v, int s) {
    unsigned lo = (unsigned)v, hi = (unsigned)(v >> 32);
    lo = __shfl_xor(lo, s);
    hi = __shfl_xor(hi, s);
    return (((unsigned long long)hi) << 32) | lo;
}

__global__ __launch_bounds__(1024)
void ttfs_kernel(const float* __restrict__ spikes,   // (BATCH, NPRE)
                 const float* __restrict__ Wt,       // (NPRE, NPOST)
                 float* __restrict__ out)            // (BATCH, NPOST)
{
    __shared__ unsigned long long sbuf[NPRE];        // sort exchange buffer
    __shared__ float4 tab[NPRE + 1];                 // (s, e^s, s*e^s, 0) sorted, +inf pad
    __shared__ int    sidx[NPRE + 4];                // sorted original indices
    __shared__ float  cA[NCH][NJ], cB[NCH][NJ];      // chunk sums
    __shared__ int    ffk[NCH][NJ];                  // chunk-found k (-1 none)
    __shared__ float  ffA[NCH][NJ], ffB[NCH][NJ];

    const int tid = threadIdx.x;
    const int b   = (int)blockIdx.x >> 1;
    const int h   = (int)blockIdx.x & 1;

    // ---- load + pack (key asc, idx asc) == u64 asc for positive floats ----
    {
        float s = spikes[b * NPRE + tid];
        unsigned long long v =
            (((unsigned long long)__float_as_uint(s)) << 32) | (unsigned)tid;

        // ---- hybrid bitonic sort: 1 elem/thread; shfl for stride<=32, LDS for >=64 ----
        for (int size = 2; size <= NPRE; size <<= 1) {
            int stride = size >> 1;
            for (; stride >= 64; stride >>= 1) {
                sbuf[tid] = v;
                __syncthreads();
                unsigned long long p = sbuf[tid ^ stride];
                __syncthreads();
                bool keepmin = (((tid & stride) == 0) == ((tid & size) == 0));
                v = ((p < v) == keepmin) ? p : v;
            }
            for (stride = (stride > 32 ? 32 : stride); stride >= 1; stride >>= 1) {
                unsigned long long p = shflxor64(v, stride);
                bool keepmin = (((tid & stride) == 0) == ((tid & size) == 0));
                v = ((p < v) == keepmin) ? p : v;
            }
        }

        // ---- tables: element `tid` of the sorted order is in v ----
        float sv = __uint_as_float((unsigned)(v >> 32));
        float e  = expf(sv);
        tab[tid]  = make_float4(sv, e, sv * e, 0.0f);
        sidx[tid] = (int)(unsigned)(v & 0xffffffffULL);
    }
    if (tid == 0) {
        tab[NPRE]  = make_float4(INFINITY, INFINITY, 0.0f, 0.0f);
        sidx[NPRE] = 0; sidx[NPRE + 1] = 0; sidx[NPRE + 2] = 0; sidx[NPRE + 3] = 0;
    }
    __syncthreads();

    // ---- chunked scan: 8 chunk-threads per neuron ----
    const int c  = tid >> 7;         // 0..7
    const int jj = tid & (NJ - 1);   // 0..127
    const int j  = h * NJ + jj;
    const float* __restrict__ Wcol = Wt + j;
    const int k0 = c * CLEN;
    const int4* __restrict__ sidx4 = (const int4*)sidx;

#define LOADW(kb, dst)                                                        \
    {                                                                         \
        _Pragma("unroll")                                                     \
        for (int q = 0; q < CH / 4; ++q) {                                    \
            int4 I = sidx4[(k0 + (kb)) / 4 + q];                              \
            dst[4 * q + 0] = Wcol[I.x * NPOST];                               \
            dst[4 * q + 1] = Wcol[I.y * NPOST];                               \
            dst[4 * q + 2] = Wcol[I.z * NPOST];                               \
            dst[4 * q + 3] = Wcol[I.w * NPOST];                               \
        }                                                                     \
    }

    // pass 1: chunk-local sums (last chunk's sums never used as offsets)
    float A = 0.0f, Bq = 0.0f;
    if (c < NCH - 1) {
        float wv[CH];
        LOADW(0, wv);
        for (int kb = 0; kb < CLEN; kb += CH) {
            float wn[CH];
            const int nb = kb + CH;
            if (nb < CLEN) LOADW(nb, wn);
#pragma unroll
            for (int i = 0; i < CH; ++i) {
                float4 t = tab[k0 + kb + i];
                A  = fmaf(wv[i], t.y, A);
                Bq = fmaf(wv[i], t.z, Bq);
            }
            if (nb < CLEN) {
#pragma unroll
                for (int i = 0; i < CH; ++i) wv[i] = wn[i];
            }
        }
    }
    cA[c][jj] = A; cB[c][jj] = Bq;
    __syncthreads();

    // pass 2: exclusive prefix over chunks
    float offA = 0.0f, offB = 0.0f;
    for (int cc = 0; cc < c; ++cc) { offA += cA[cc][jj]; offB += cB[cc][jj]; }

    // pass 3: scan chunk for first membrane crossing: V(s_{k+1}) >= 1
    A = offA; Bq = offB;
    int   fk = -1; float fA = 0.0f, fB = 0.0f;
    bool  done = false;
    {
        float4 tprev = tab[k0];
        float wv[CH];
        LOADW(0, wv);
        for (int kb = 0; kb < CLEN; kb += CH) {
            float wn[CH];
            const int nb = kb + CH;
            if (nb < CLEN) LOADW(nb, wn);
#pragma unroll
            for (int i = 0; i < CH; ++i) {
                const int k = k0 + kb + i;
                float4 tn = tab[k + 1];            // rolling: serves gate@k and accum@k+1
                A  = fmaf(wv[i], tprev.y, A);
                Bq = fmaf(wv[i], tprev.z, Bq);
                if (!done) {
                    float gate = fmaf(A, tn.x, -Bq);
                    if (gate >= tn.y) { fA = A; fB = Bq; fk = k; done = true; }
                }
                tprev = tn;
            }
            if (__all(done)) break;
            if (nb < CLEN) {
#pragma unroll
                for (int i = 0; i < CH; ++i) wv[i] = wn[i];
            }
        }
    }
    ffk[c][jj] = fk; ffA[c][jj] = fA; ffB[c][jj] = fB;
    __syncthreads();

    // ---- resolve: one thread per neuron picks earliest chunk, Lambert W once ----
    if (tid < NJ) {
        const int jr = tid;
        int fk2 = -1; float fA2 = 0.0f, fB2 = 0.0f;
#pragma unroll
        for (int cc = 0; cc < NCH; ++cc) {
            int k = ffk[cc][jr];
            if (fk2 < 0 && k >= 0) { fk2 = k; fA2 = ffA[cc][jr]; fB2 = ffB[cc][jr]; }
        }
        float result = INFINITY;
        const float INV_E = 0.36787944117144233f;
        const float* __restrict__ Wc2 = Wt + h * NJ + jr;
        if (fk2 >= 0) {
            float r  = fB2 / fA2;
            float ez = expf(fminf(fmaxf(r, -30.0f), 30.0f));
            float z  = -ez / fA2;
            bool valid = (fA2 > 0.0f) && (z >= -INV_E);
            float t = r - lambertw0_f(z);
            bool ok = valid && (t >= tab[fk2].x) && (fk2 == NPRE - 1 || t <= tab[fk2 + 1].x);
            if (ok) {
                result = t;
            } else {
                // rare fp-edge fallback: faithful sequential scan from fk2+1
                float A2 = fA2, B2 = fB2;
                for (int k = fk2 + 1; k < NPRE; ++k) {
                    float w = Wc2[sidx[k] * NPOST];
                    float4 t3 = tab[k];
                    A2 = fmaf(w, t3.y, A2);
                    B2 = fmaf(w, t3.z, B2);
                    if (A2 <= 0.0f) continue;
                    float r2  = B2 / A2;
                    float ez2 = expf(fminf(fmaxf(r2, -30.0f), 30.0f));
                    float z2  = -ez2 / A2;
                    if (z2 < -INV_E) continue;
                    float t2 = r2 - lambertw0_f(z2);
                    if (t2 < t3.x) continue;
                    if (k < NPRE - 1 && t2 > tab[k + 1].x) continue;
                    result = t2;
                    break;
                }
            }
        }
        out[b * NPOST + h * NJ + jr] = result;
    }
}

extern "C" void kernel_launch(void* const* d_in, const int* in_sizes, int n_in,
                              void* d_out, int out_size, void* d_ws, size_t ws_size,
                              hipStream_t stream) {
    const float* spikes  = (const float*)d_in[0];   // (128, 1024) f32
    const float* weights = (const float*)d_in[1];   // (1024, 256) f32
    float* outp = (float*)d_out;                    // (128, 256) f32
    ttfs_kernel<<<dim3(BATCH * 2), dim3(1024), 0, stream>>>(spikes, weights, outp);
}

// Round 4
// 28.191 us; speedup vs baseline: 2.1226x; 1.1032x over previous
//
#include <hip/hip_runtime.h>
#include <math.h>

#define BATCH 128
#define NPRE  1024
#define NPOST 256
#define NCH   8      // k-chunks per neuron
#define CLEN  128    // NPRE / NCH
#define NJ    128    // neurons per block (NPOST/2)
#define CH    16     // weight prefetch batch

__device__ __forceinline__ float rlf(float v, int lane) {
    // wave-uniform lane -> v_readlane_b32 (no LDS traffic)
    return __int_as_float(__builtin_amdgcn_readlane(__float_as_int(v), lane));
}

__device__ __forceinline__ float lambertw0_f(float z) {
    // Principal branch for z in [-1/e, 0); mirrors reference (clip + init + 12 Halley)
    const float INV_E = 0.36787944117144233f;
    float zc = fminf(fmaxf(z, -INV_E + 1e-8f), -1e-30f);
    float w;
    if (zc < -0.2f) {
        w = -1.0f + sqrtf(2.0f * (1.0f + 2.718281828459045f * zc));
    } else {
        w = zc * (1.0f - zc);
    }
#pragma unroll
    for (int it = 0; it < 12; ++it) {
        float ew  = expf(w);
        float f   = w * ew - zc;
        float wp1 = w + 1.0f;
        w = w - f / (ew * wp1 - (w + 2.0f) * f / (2.0f * wp1));
    }
    return w;
}

__device__ __forceinline__ unsigned long long shflxor64(unsigned long long v, int s) {
    unsigned lo = (unsigned)v, hi = (unsigned)(v >> 32);
    lo = __shfl_xor(lo, s);
    hi = __shfl_xor(hi, s);
    return (((unsigned long long)hi) << 32) | lo;
}

__global__ __launch_bounds__(1024)
void ttfs_kernel(const float* __restrict__ spikes,   // (BATCH, NPRE)
                 const float* __restrict__ Wt,       // (NPRE, NPOST)
                 float* __restrict__ out)            // (BATCH, NPOST)
{
    __shared__ unsigned long long sbuf[NPRE];        // sort exchange buffer
    __shared__ float4 tab[NPRE + 1];                 // (s, e^s, s*e^s, 0) sorted, +inf pad
    __shared__ int    sidx[NPRE + 4];                // sorted original indices
    __shared__ float  cA[NCH][NJ], cB[NCH][NJ];      // chunk sums
    __shared__ int    ffk[NCH][NJ];                  // chunk-found k (-1 none)
    __shared__ float  ffA[NCH][NJ], ffB[NCH][NJ];

    const int tid = threadIdx.x;
    const int b   = (int)blockIdx.x >> 1;
    const int h   = (int)blockIdx.x & 1;

    // ---- load + pack (key asc, idx asc) == u64 asc for positive floats ----
    {
        float s = spikes[b * NPRE + tid];
        unsigned long long v =
            (((unsigned long long)__float_as_uint(s)) << 32) | (unsigned)tid;

        // ---- hybrid bitonic sort: 1 elem/thread; shfl for stride<=32, LDS for >=64 ----
        for (int size = 2; size <= NPRE; size <<= 1) {
            int stride = size >> 1;
            for (; stride >= 64; stride >>= 1) {
                sbuf[tid] = v;
                __syncthreads();
                unsigned long long p = sbuf[tid ^ stride];
                __syncthreads();
                bool keepmin = (((tid & stride) == 0) == ((tid & size) == 0));
                v = ((p < v) == keepmin) ? p : v;
            }
            for (stride = (stride > 32 ? 32 : stride); stride >= 1; stride >>= 1) {
                unsigned long long p = shflxor64(v, stride);
                bool keepmin = (((tid & stride) == 0) == ((tid & size) == 0));
                v = ((p < v) == keepmin) ? p : v;
            }
        }

        float sv = __uint_as_float((unsigned)(v >> 32));
        float e  = expf(sv);
        tab[tid]  = make_float4(sv, e, sv * e, 0.0f);
        sidx[tid] = (int)(unsigned)(v & 0xffffffffULL);
    }
    if (tid == 0) {
        tab[NPRE]  = make_float4(INFINITY, INFINITY, 0.0f, 0.0f);
        sidx[NPRE] = 0; sidx[NPRE + 1] = 0; sidx[NPRE + 2] = 0; sidx[NPRE + 3] = 0;
    }
    __syncthreads();

    // ---- chunked scan: 8 chunk-threads per neuron ----
    const int c  = tid >> 7;         // 0..7
    const int jj = tid & (NJ - 1);   // 0..127
    const int j  = h * NJ + jj;
    const float* __restrict__ Wcol = Wt + j;
    const int k0 = c * CLEN;
    const int4* __restrict__ sidx4 = (const int4*)sidx;

    // per-lane distributed table: lane L holds entries k0+L and k0+64+L
    const int L = tid & 63;
    const float4 tA4  = tab[k0 + L];
    const float4 tB4  = tab[k0 + 64 + L];
    const float4 tEnd = tab[k0 + CLEN];   // chunk boundary (last chunk: +inf pad)

#define LOADW(kb, dst)                                                        \
    {                                                                         \
        _Pragma("unroll")                                                     \
        for (int q = 0; q < CH / 4; ++q) {                                    \
            int4 I = sidx4[(k0 + (kb)) / 4 + q];                              \
            dst[4 * q + 0] = Wcol[I.x * NPOST];                               \
            dst[4 * q + 1] = Wcol[I.y * NPOST];                               \
            dst[4 * q + 2] = Wcol[I.z * NPOST];                               \
            dst[4 * q + 3] = Wcol[I.w * NPOST];                               \
        }                                                                     \
    }

    // pass 1: chunk-local sums (last chunk's sums never used as offsets)
    float A = 0.0f, Bq = 0.0f;
    if (c < NCH - 1) {
        float wv[CH];
        LOADW(0, wv);
        for (int kb = 0; kb < CLEN; kb += CH) {
            float wn[CH];
            const int nb = kb + CH;
            if (nb < CLEN) LOADW(nb, wn);
            const bool hi   = kb >= 64;
            const float eH  = hi ? tB4.y : tA4.y;
            const float seH = hi ? tB4.z : tA4.z;
#pragma unroll
            for (int i = 0; i < CH; ++i) {
                const int Lr = (kb + i) & 63;
                float ek  = rlf(eH,  Lr);
                float sek = rlf(seH, Lr);
                A  = fmaf(wv[i], ek,  A);
                Bq = fmaf(wv[i], sek, Bq);
            }
            if (nb < CLEN) {
#pragma unroll
                for (int i = 0; i < CH; ++i) wv[i] = wn[i];
            }
        }
    }
    cA[c][jj] = A; cB[c][jj] = Bq;
    __syncthreads();

    // pass 2: exclusive prefix over chunks
    float offA = 0.0f, offB = 0.0f;
    for (int cc = 0; cc < c; ++cc) { offA += cA[cc][jj]; offB += cB[cc][jj]; }

    // pass 3: delayed-gate scan. Gate at iteration kk tests window k0+kk-1:
    //   V(s_{k}) >= 1  <=>  A_{<k}*s_k - B_{<k} >= e^{s_k}
    A = offA; Bq = offB;
    int   fk = -1; float fA = 0.0f, fB = 0.0f;
    bool  done = false;
    if (c > 0) {
        // pre-gate: membrane already crossed before k0 -> earlier chunk owns it.
        // 1e-5 relative margin so cross-chunk ulp reordering can never flip this.
        float s0 = rlf(tA4.x, 0), e0 = rlf(tA4.y, 0);
        done = fmaf(offA, s0, -offB) >= e0 * 1.00001f;
    }
    if (!__all(done)) {
        float wv[CH];
        LOADW(0, wv);
        for (int kb = 0; kb < CLEN; kb += CH) {
            float wn[CH];
            const int nb = kb + CH;
            if (nb < CLEN) LOADW(nb, wn);
            const bool hi   = kb >= 64;
            const float sH  = hi ? tB4.x : tA4.x;
            const float eH  = hi ? tB4.y : tA4.y;
            const float seH = hi ? tB4.z : tA4.z;
#pragma unroll
            for (int i = 0; i < CH; ++i) {
                const int kk = kb + i;
                const int Lr = kk & 63;
                float sk  = rlf(sH,  Lr);
                float ek  = rlf(eH,  Lr);
                float sek = rlf(seH, Lr);
                if (!done && kk > 0) {
                    float gate = fmaf(A, sk, -Bq);
                    if (gate >= ek) { fA = A; fB = Bq; fk = k0 + kk - 1; done = true; }
                }
                A  = fmaf(wv[i], ek,  A);
                Bq = fmaf(wv[i], sek, Bq);
            }
            if (__all(done)) break;
            if (nb < CLEN) {
#pragma unroll
                for (int i = 0; i < CH; ++i) wv[i] = wn[i];
            }
        }
        if (!done) {
            // tail gate: window k0+CLEN-1 against chunk boundary (or +inf pad)
            float gate = fmaf(A, tEnd.x, -Bq);
            if (gate >= tEnd.y) { fA = A; fB = Bq; fk = k0 + CLEN - 1; }
        }
    }
    ffk[c][jj] = fk; ffA[c][jj] = fA; ffB[c][jj] = fB;
    __syncthreads();

    // ---- resolve: one thread per neuron picks earliest chunk, Lambert W once ----
    if (tid < NJ) {
        const int jr = tid;
        int fk2 = -1; float fA2 = 0.0f, fB2 = 0.0f;
#pragma unroll
        for (int cc = 0; cc < NCH; ++cc) {
            int k = ffk[cc][jr];
            if (fk2 < 0 && k >= 0) { fk2 = k; fA2 = ffA[cc][jr]; fB2 = ffB[cc][jr]; }
        }
        float result = INFINITY;
        const float INV_E = 0.36787944117144233f;
        const float* __restrict__ Wc2 = Wt + h * NJ + jr;
        if (fk2 >= 0) {
            float r  = fB2 / fA2;
            float ez = expf(fminf(fmaxf(r, -30.0f), 30.0f));
            float z  = -ez / fA2;
            bool valid = (fA2 > 0.0f) && (z >= -INV_E);
            float t = r - lambertw0_f(z);
            bool ok = valid && (t >= tab[fk2].x) && (fk2 == NPRE - 1 || t <= tab[fk2 + 1].x);
            if (ok) {
                result = t;
            } else {
                // rare fp-edge fallback: faithful sequential scan from fk2+1
                float A2 = fA2, B2 = fB2;
                for (int k = fk2 + 1; k < NPRE; ++k) {
                    float w = Wc2[sidx[k] * NPOST];
                    float4 t3 = tab[k];
                    A2 = fmaf(w, t3.y, A2);
                    B2 = fmaf(w, t3.z, B2);
                    if (A2 <= 0.0f) continue;
                    float r2  = B2 / A2;
                    float ez2 = expf(fminf(fmaxf(r2, -30.0f), 30.0f));
                    float z2  = -ez2 / A2;
                    if (z2 < -INV_E) continue;
                    float t2 = r2 - lambertw0_f(z2);
                    if (t2 < t3.x) continue;
                    if (k < NPRE - 1 && t2 > tab[k + 1].x) continue;
                    result = t2;
                    break;
                }
            }
        }
        out[b * NPOST + h * NJ + jr] = result;
    }
}

extern "C" void kernel_launch(void* const* d_in, const int* in_sizes, int n_in,
                              void* d_out, int out_size, void* d_ws, size_t ws_size,
                              hipStream_t stream) {
    const float* spikes  = (const float*)d_in[0];   // (128, 1024) f32
    const float* weights = (const float*)d_in[1];   // (1024, 256) f32
    float* outp = (float*)d_out;                    // (128, 256) f32
    ttfs_kernel<<<dim3(BATCH * 2), dim3(1024), 0, stream>>>(spikes, weights, outp);
}